// Round 7
// baseline (727.162 us; speedup 1.0000x reference)
//
#include <hip/hip_runtime.h>
#include <cstdint>

typedef _Float16 half8 __attribute__((ext_vector_type(8)));
typedef _Float16 half4v __attribute__((ext_vector_type(4)));
typedef float f32x4 __attribute__((ext_vector_type(4)));

__device__ __forceinline__ void async_copy16(const void* g, void* l) {
    __builtin_amdgcn_global_load_lds((const __attribute__((address_space(1))) void*)g,
                                     (__attribute__((address_space(3))) void*)l, 16, 0, 0);
}

// ---------------------------------------------------------------------------
// prep: w_s = kernel * (1/32)   [= 32 * (kernel/1024)], plus transposed copy.
// ---------------------------------------------------------------------------
__global__ __launch_bounds__(256) void prep_w(const float* __restrict__ K,
                                              _Float16* __restrict__ w0,
                                              _Float16* __restrict__ w0T) {
    __shared__ float tile[64][65];
    const int t  = threadIdx.x;
    const int bi = blockIdx.y * 64;
    const int bj = blockIdx.x * 64;
    const int r0 = t >> 4;
    const int c4 = (t & 15) * 4;
#pragma unroll
    for (int rr = 0; rr < 4; ++rr) {
        int r = r0 + rr * 16;
        f32x4 v = *(const f32x4*)&K[(size_t)(bi + r) * 1024 + bj + c4];
        v *= 0.03125f;
        half4v h;
        h[0] = (_Float16)v[0]; h[1] = (_Float16)v[1];
        h[2] = (_Float16)v[2]; h[3] = (_Float16)v[3];
        *(half4v*)&w0[(size_t)(bi + r) * 1024 + bj + c4] = h;
        tile[r][c4 + 0] = v[0]; tile[r][c4 + 1] = v[1];
        tile[r][c4 + 2] = v[2]; tile[r][c4 + 3] = v[3];
    }
    __syncthreads();
    const int cT = t >> 4;
    const int rT = (t & 15) * 4;
#pragma unroll
    for (int cc = 0; cc < 4; ++cc) {
        int c = cT + cc * 16;
        half4v h;
        h[0] = (_Float16)tile[rT + 0][c]; h[1] = (_Float16)tile[rT + 1][c];
        h[2] = (_Float16)tile[rT + 2][c]; h[3] = (_Float16)tile[rT + 3][c];
        *(half4v*)&w0T[(size_t)(bj + c) * 1024 + bi + rT] = h;
    }
}

// ---------------------------------------------------------------------------
// small 1024x1024x1024 GEMM:  C[m][n] = sum_k A[m][k] * BT[n][k]
// EPI==0: out = (fp16)acc                  (S_s = w_s^T w_s, via A=BT=wT)
// EPI==1: w' = 1.5*wcur - (0.5/1024)*acc   (+ transposed copy)
// v4 (rounds 4-5, PASSED twice): 4-buffer LDS (128 KB), 3-deep glds
// prefetch, counted vmcnt(8) steady, tail vmcnt(4)/vmcnt(0).
// NOTE: per-launch chain. Round-1: persistent full grid barrier = ~30us/phase.
// Round-6: dataflow band-flag fusion RACES nondeterministically (bench absmax
// varied across replays) — cross-XCD flag protocol unproven; do not re-fuse
// without a fundamentally stronger sync design.
// ---------------------------------------------------------------------------
template <int EPI>
__global__ __launch_bounds__(512) void gemm1k(const _Float16* __restrict__ A,
                                              const _Float16* __restrict__ BT,
                                              const _Float16* __restrict__ wcur,
                                              _Float16* __restrict__ out,
                                              _Float16* __restrict__ outT) {
    __shared__ _Float16 sA[4][8192];   // 64 rows x 128 halves per buf (16 KB)
    __shared__ _Float16 sB[4][8192];   // total 128 KB
    const int t = threadIdx.x;
    const int b = blockIdx.x;
    const int xcd = b & 7, j = b >> 3;
    const int m0 = (((xcd & 1) << 3) + (j & 7)) << 6;   // 16 m-tiles
    const int n0 = (((xcd >> 1) << 2) + (j >> 3)) << 6; // 16 n-tiles
    const int ln = t & 63, wv = t >> 6;
    const int wm = wv >> 1, wn = wv & 1;     // 4 x 2 waves
    const int q  = ln >> 4, l15 = ln & 15;
    const int row0 = m0 + wm * 16 + q * 4;

    // EPI==1: wcur prefetch issued BEFORE the stages -> oldest in the vmcnt
    // FIFO; counted waits retire it first (harmless).
    float wpre[2][4];
    if (EPI == 1) {
#pragma unroll
        for (int jn = 0; jn < 2; ++jn) {
            int col = n0 + wn * 32 + jn * 16 + l15;
#pragma unroll
            for (int r = 0; r < 4; ++r)
                wpre[jn][r] = (float)wcur[(size_t)(row0 + r) * 1024 + col];
        }
    }

    f32x4 acc[2];
#pragma unroll
    for (int jn = 0; jn < 2; ++jn) {
        acc[jn][0] = 0.f; acc[jn][1] = 0.f;
        acc[jn][2] = 0.f; acc[jn][3] = 0.f;
    }

    auto stage = [&](int buf, int k0) {   // 4 vmcnt entries per thread
#pragma unroll
        for (int rnd = 0; rnd < 2; ++rnd) {
            int c = t + rnd * 512;          // granule 0..1023 (16 per row)
            int row = c >> 4, g = c & 15;
            int gs = g ^ (row & 15);        // XOR swizzle
            async_copy16(A + (size_t)(m0 + row) * 1024 + k0 + gs * 8, &sA[buf][c * 8]);
            async_copy16(BT + (size_t)(n0 + row) * 1024 + k0 + gs * 8, &sB[buf][c * 8]);
        }
    };
    auto frag = [&](const _Float16* s, int row, int kc) -> half8 {
        return *(const half8*)&s[row * 128 + ((kc ^ (row & 15)) << 3)];
    };
    auto dostep = [&](int buf) {
#pragma unroll
        for (int kk = 0; kk < 4; ++kk) {
            half8 a0 = frag(sA[buf], wm * 16 + l15, kk * 4 + q);
            half8 b0 = frag(sB[buf], wn * 32 + 0  + l15, kk * 4 + q);
            half8 b1 = frag(sB[buf], wn * 32 + 16 + l15, kk * 4 + q);
            acc[0] = __builtin_amdgcn_mfma_f32_16x16x32_f16(a0, b0, acc[0], 0, 0, 0);
            acc[1] = __builtin_amdgcn_mfma_f32_16x16x32_f16(a0, b1, acc[1], 0, 0, 0);
        }
    };

    stage(0, 0);
    stage(1, 128);
    stage(2, 256);
    // steady: at top of it, outstanding = stage(it)+stage(it+1)+stage(it+2)
    // = 12 entries; vmcnt(8) retires stage(it) only.
#pragma unroll 1
    for (int it = 0; it < 6; ++it) {
        asm volatile("s_waitcnt vmcnt(8)\n\ts_barrier" ::: "memory");
        if (it < 5) stage((it + 3) & 3, (it + 3) * 128);
        dostep(it & 3);
    }
    asm volatile("s_waitcnt vmcnt(4)\n\ts_barrier" ::: "memory");  // stage(6) done
    dostep(2);   // tile 6 -> buf 2
    asm volatile("s_waitcnt vmcnt(0)\n\ts_barrier" ::: "memory");  // stage(7) done
    dostep(3);   // tile 7 -> buf 3

    // epilogue
#pragma unroll
    for (int jn = 0; jn < 2; ++jn) {
        int col = n0 + wn * 32 + jn * 16 + l15;
        if (EPI == 0) {
#pragma unroll
            for (int r = 0; r < 4; ++r)
                out[(size_t)(row0 + r) * 1024 + col] = (_Float16)acc[jn][r];
        } else {
            half4v hT;
#pragma unroll
            for (int r = 0; r < 4; ++r) {
                float nv  = 1.5f * wpre[jn][r] - 4.8828125e-4f * acc[jn][r];
                _Float16 h = (_Float16)nv;
                out[(size_t)(row0 + r) * 1024 + col] = h;
                hT[r] = h;
            }
            *(half4v*)&outT[(size_t)col * 1024 + row0] = hT;
        }
    }
}

// ---------------------------------------------------------------------------
// big GEMM: Y[32768][1024] = (1/32) * X(f32, cvt->f16) * w_s  + bias
// v9 = round-5's v7 main loop (256x256, BK=64, 8 waves 2m x 4n, counted
// vmcnt(8), B glds pre-swizzled src, A reg-staged swizzled ds_write —
// verified: bank-conflicts 0, FETCH 99 MB) + FIXED LDS-bounce epilogue.
// Round-6 bug: reader covered only 25% of columns (k<4 instead of k<16);
// now each thread streams its row-quarter (16 x f32x4 = 64 contiguous
// floats), full 128x256 coverage per half-tile.
// Motivation (round-5 counters): WRITE_SIZE 181 MB vs 128 ideal — scalar
// 64B-granule Y stores caused partial-line writebacks under X-stream
// eviction; full-line f32x4 row streams fix it.
// ---------------------------------------------------------------------------
__global__ __launch_bounds__(512) void gemm_big(const float* __restrict__ X,
                                                const _Float16* __restrict__ BT,
                                                const float* __restrict__ bias,
                                                float* __restrict__ Y) {
    __shared__ _Float16 smem[65536];       // 128 KB: sA = [0,64KB), sB = [64,128)
    _Float16* sAb = smem;
    _Float16* sBb = smem + 32768;
    const int t    = threadIdx.x;
    const int b    = blockIdx.x;           // 0..511
    const int xcd  = b & 7;
    const int j    = b >> 3;               // 0..63
    const int rnd_ = j >> 5;               // dispatch round 0..1
    const int jj   = j & 31;
    const int mt   = rnd_ * 64 + xcd * 8 + (jj >> 2);  // 0..127
    const int nt   = jj & 3;                           // 0..3
    const int m0 = mt * 256, n0 = nt * 256;
    const int ln = t & 63, wv = t >> 6;    // 8 waves
    const int wm = wv >> 2, wn = wv & 3;   // 2m x 4n
    const int q  = ln >> 4, l15 = ln & 15;

    f32x4 acc[8][4];
#pragma unroll
    for (int i = 0; i < 8; ++i)
#pragma unroll
        for (int jn = 0; jn < 4; ++jn) {
            acc[i][jn][0] = 0.f; acc[i][jn][1] = 0.f;
            acc[i][jn][2] = 0.f; acc[i][jn][3] = 0.f;
        }

    auto loadX = [&](int k0, f32x4* va) {   // 8 vmcnt entries, coalesced
#pragma unroll
        for (int rnd = 0; rnd < 4; ++rnd) {
            int c = t + rnd * 512;
            int row = c >> 3, g = c & 7;
            const float* p = &X[(size_t)(m0 + row) * 1024 + k0 + g * 8];
            va[rnd * 2 + 0] = *(const f32x4*)p;
            va[rnd * 2 + 1] = *(const f32x4*)(p + 4);
        }
    };
    auto writeA = [&](int buf, const f32x4* va) {  // swizzled ds_write_b128
#pragma unroll
        for (int rnd = 0; rnd < 4; ++rnd) {
            int c = t + rnd * 512;
            int row = c >> 3, g = c & 7;
            half8 h;
#pragma unroll
            for (int i = 0; i < 4; ++i) {
                h[i]     = (_Float16)va[rnd * 2 + 0][i];
                h[4 + i] = (_Float16)va[rnd * 2 + 1][i];
            }
            *(half8*)&sAb[buf * 16384 + row * 64 + ((g ^ (row & 7)) << 3)] = h;
        }
    };
    auto stageB = [&](int buf, int k0) {    // 4 vmcnt entries; linear dest
#pragma unroll
        for (int rnd = 0; rnd < 4; ++rnd) {
            int c = t + rnd * 512;
            int row = c >> 3, g = c & 7;
            int gs = g ^ (row & 7);         // inverse-swizzled source
            async_copy16(BT + (size_t)(n0 + row) * 1024 + k0 + gs * 8,
                         &sBb[buf * 16384 + c * 8]);
        }
    };
    auto compute = [&](int tb) {
        const _Float16* A_ = sAb + (tb & 1) * 16384;
        const _Float16* B_ = sBb + (tb & 1) * 16384;
#pragma unroll
        for (int kk = 0; kk < 2; ++kk) {
            const int gidx = kk * 4 + q;
            half8 a[8], bf[4];
#pragma unroll
            for (int im = 0; im < 8; ++im) {
                int row = wm * 128 + im * 16 + l15;
                a[im] = *(const half8*)&A_[row * 64 + ((gidx ^ (row & 7)) << 3)];
            }
#pragma unroll
            for (int jn = 0; jn < 4; ++jn) {
                int row = wn * 64 + jn * 16 + l15;
                bf[jn] = *(const half8*)&B_[row * 64 + ((gidx ^ (row & 7)) << 3)];
            }
#pragma unroll
            for (int im = 0; im < 8; ++im)
#pragma unroll
                for (int jn = 0; jn < 4; ++jn)
                    acc[im][jn] = __builtin_amdgcn_mfma_f32_16x16x32_f16(
                        a[im], bf[jn], acc[im][jn], 0, 0, 0);
        }
    };

    f32x4 vaA[8], vaB[8];
    loadX(0, vaA);
    stageB(0, 0);
    writeA(0, vaA);
    loadX(64, vaB);

#define BODY(T, VLD, VWR, CNT)                                                \
    {                                                                         \
        asm volatile("s_waitcnt vmcnt(" #CNT ") lgkmcnt(0)\n\ts_barrier" ::: "memory"); \
        if ((T) + 1 < 16) stageB(((T) + 1) & 1, ((T) + 1) * 64);              \
        if ((T) + 2 < 16) loadX(((T) + 2) * 64, VLD);                         \
        if ((T) + 1 < 16) writeA(((T) + 1) & 1, VWR);                         \
        compute(T);                                                           \
    }

#pragma unroll 1
    for (int tp = 0; tp < 7; ++tp) {
        int te = tp * 2;
        BODY(te, vaA, vaB, 8);
        BODY(te + 1, vaB, vaA, 8);
    }
    BODY(14, vaA, vaB, 8);
    BODY(15, vaB, vaA, 0);
#undef BODY

    // ---- LDS-bounce epilogue (FIXED coverage): full-line Y stores ----
    // Writer (4 waves with wm==wmh): logical (lr, c) -> fl[lr*256 + (c^swz)],
    // swz = (lr&7)<<2 (float granules; 2-way bank conflicts only).
    // Reader (all 512 threads): row lr = t>>2; thread streams its contiguous
    // 64-float quarter-row c in [(t&3)*64, +64) as 16 x f32x4 (4-aligned, so
    // (c+d)^swz == (c^swz)+d for d<4 — identical swizzle both sides).
    float bv[4];
#pragma unroll
    for (int jn = 0; jn < 4; ++jn) bv[jn] = bias[n0 + wn * 64 + jn * 16 + l15];
    float* fl = (float*)smem;              // 128 rows x 256 f32 = 128 KB
#pragma unroll 1
    for (int wmh = 0; wmh < 2; ++wmh) {
        __syncthreads();                   // LDS free / prev pass read done
        if (wm == wmh) {
#pragma unroll
            for (int im = 0; im < 8; ++im)
#pragma unroll
                for (int jn = 0; jn < 4; ++jn)
#pragma unroll
                    for (int r = 0; r < 4; ++r) {
                        int lr = im * 16 + q * 4 + r;
                        int c  = wn * 64 + jn * 16 + l15;
                        fl[lr * 256 + (c ^ ((lr & 7) << 2))] =
                            acc[im][jn][r] * 0.03125f + bv[jn];
                    }
        }
        __syncthreads();
        {
            int lr = t >> 2;
            int c0 = (t & 3) * 64;
#pragma unroll
            for (int k = 0; k < 16; ++k) {
                int c = c0 + k * 4;
                f32x4 v = *(const f32x4*)&fl[lr * 256 + (c ^ ((lr & 7) << 2))];
                *(f32x4*)&Y[(size_t)(m0 + wmh * 128 + lr) * 1024 + n0 + c] = v;
            }
        }
    }
}

// ---------------------------------------------------------------------------
extern "C" void kernel_launch(void* const* d_in, const int* in_sizes, int n_in,
                              void* d_out, int out_size, void* d_ws, size_t ws_size,
                              hipStream_t stream) {
    (void)in_sizes; (void)n_in; (void)out_size; (void)ws_size;
    const float* x    = (const float*)d_in[0];
    const float* kern = (const float*)d_in[1];
    const float* bias = (const float*)d_in[2];
    float* y = (float*)d_out;

    char* ws = (char*)d_ws;
    const size_t SZ = (size_t)1024 * 1024 * sizeof(_Float16);  // 2 MB
    _Float16* wh[2] = {(_Float16*)(ws + 0 * SZ), (_Float16*)(ws + 1 * SZ)};
    _Float16* wT[2] = {(_Float16*)(ws + 2 * SZ), (_Float16*)(ws + 3 * SZ)};
    _Float16* Sh    = (_Float16*)(ws + 4 * SZ);

    prep_w<<<dim3(16, 16), 256, 0, stream>>>(kern, wh[0], wT[0]);

    for (int it = 0; it < 20; ++it) {
        int c = it & 1, n = c ^ 1;
        // S_s = w_s^T w_s : A = BT = wT (both row-slabs of w^T, k contiguous)
        gemm1k<0><<<256, 512, 0, stream>>>(wT[c], wT[c], nullptr, Sh, nullptr);
        // w_next = 1.5 w - (0.5/1024) * (w_s * S_s); BT = S (symmetric)
        gemm1k<1><<<256, 512, 0, stream>>>(wh[c], Sh, wh[c], wh[n], wT[n]);
    }
    // final: y = (1/32) x * w_s + bias ; BT = wT (final parity lands in slot 0)
    gemm_big<<<512, 512, 0, stream>>>(x, wT[0], bias, y);
}